// Round 3
// baseline (624.355 us; speedup 1.0000x reference)
//
#include <hip/hip_runtime.h>
#include <stdint.h>

// Bahdanau additive attention. S=2048, B=32, H=1024.
// context[b,h] = sum_s softmax_s(mask(v . tanh(W1 hs + b1 + W2 h + b2))) * hs
//
// Fast path (needs ~138.4 MB workspace):
//  0) prep: fused {hs,W1 -> f16} + {t2 = hidden.W2^T + b1 + b2}
//  2) gemm_energy_8p: 256x256x(BK=64) f16 MFMA, 8 waves (2Mx4N), LAGGED
//     4-phase/K-tile schedule: phase p issues ds_reads for quadrant p+1;
//     MFMA clusters consume reads issued one full phase (>=1 barrier) earlier
//     -> no exposed lgkm wait. Stages early (ph1: A(t+1) both halves,
//     ph2: B(t+1) both halves) so tile-end vmcnt(0) waits on ~3000-cyc-old
//     loads (free) and overwrite-safety is barrier-bounded by construction.
//     XOR-swizzled LDS, global_load_lds 16B, bijective XCD swizzle,
//     t2-in-LDS + tanh+dot(v) + DPP-reduce epilogue -> epart[p][b][s].
//  3) softmax16t  4) context_f16t  5) ctx_reduce32
// Fallback path = round-2 kernels (3.4 MB ws), known-passing, own layouts.

#define SS 2048
#define BB 32
#define HH 1024
#define MM (SS*BB)   // 65536

typedef _Float16 f16;
typedef __attribute__((ext_vector_type(8))) _Float16 f16x8;
typedef __attribute__((ext_vector_type(4))) _Float16 f16x4;
typedef __attribute__((ext_vector_type(4))) float   floatx4;

__device__ __forceinline__ float tanh_fast(float x) {
  float e = __expf(2.0f * x);
  return 1.0f - 2.0f / (e + 1.0f);
}

// async global->LDS, 16B/lane. LDS dest = wave-uniform base + lane*16.
__device__ __forceinline__ void gload16(void* lds_base, const void* gptr) {
  __builtin_amdgcn_global_load_lds(
      (const __attribute__((address_space(1))) uint32_t*)(uintptr_t)gptr,
      (__attribute__((address_space(3))) uint32_t*)(uint32_t)(uintptr_t)lds_base,
      16, 0, 0);
}

// raw barrier with compiler memory fence (no waitcnt drain): the lagged
// schedule moves ds_read consumption across barriers, so the compiler must
// not hoist/sink LDS ops past these.
#define BARm()  asm volatile("s_barrier" ::: "memory")
#define VMC0()  asm volatile("s_waitcnt vmcnt(0)" ::: "memory")

// 16-lane butterfly sum via DPP: xor1, xor2 (quad_perm), xor7 (row_half_mirror),
// xor15 (row_mirror). Pure VALU - no LDS pipe.
__device__ __forceinline__ float dpp_red16(float x) {
  int t;
  t = __builtin_amdgcn_update_dpp(0, __float_as_int(x), 0xB1, 0xF, 0xF, true);
  x += __int_as_float(t);
  t = __builtin_amdgcn_update_dpp(0, __float_as_int(x), 0x4E, 0xF, 0xF, true);
  x += __int_as_float(t);
  t = __builtin_amdgcn_update_dpp(0, __float_as_int(x), 0x141, 0xF, 0xF, true);
  x += __int_as_float(t);
  t = __builtin_amdgcn_update_dpp(0, __float_as_int(x), 0x140, 0xF, 0xF, true);
  x += __int_as_float(t);
  return x;
}

// ---------------- prep: fp32->f16 convert (hs, W1) + t2 ----------------
__global__ __launch_bounds__(256) void prep_kernel(
    const float* __restrict__ hs, const float* __restrict__ W1,
    const float* __restrict__ hidden, const float* __restrict__ W2,
    const float* __restrict__ b1, const float* __restrict__ b2,
    f16* __restrict__ hsf, f16* __restrict__ W1f, float* __restrict__ t2)
{
  const int bid = blockIdx.x;
  if (bid < 33280) {
    const size_t NH = (size_t)MM * HH;   // 64M floats
    size_t g0 = (size_t)bid * 2048 + threadIdx.x * 4;
    const float* src;
    f16* dst;
    if (g0 < NH) { src = hs; dst = hsf; }
    else         { src = W1 - NH; dst = W1f - NH; }  // offset fold
    floatx4 a = *(const floatx4*)&src[g0];
    floatx4 b = *(const floatx4*)&src[g0 + 1024];
    f16x4 oa = {(f16)a.x,(f16)a.y,(f16)a.z,(f16)a.w};
    f16x4 ob = {(f16)b.x,(f16)b.y,(f16)b.z,(f16)b.w};
    *(f16x4*)&dst[g0] = oa;
    *(f16x4*)&dst[g0 + 1024] = ob;
  } else {
    const int gw   = (bid - 33280) * 4 + (threadIdx.x >> 6);
    const int n    = gw >> 5;
    const int b    = gw & 31;
    const int lane = threadIdx.x & 63;
    float acc = 0.f;
#pragma unroll
    for (int q = 0; q < 4; ++q) {
      floatx4 hv = *(const floatx4*)&hidden[b * HH + q * 256 + lane * 4];
      floatx4 wv = *(const floatx4*)&W2[(size_t)n * HH + q * 256 + lane * 4];
      acc += hv.x * wv.x + hv.y * wv.y + hv.z * wv.z + hv.w * wv.w;
    }
#pragma unroll
    for (int off = 1; off < 64; off <<= 1) acc += __shfl_xor(acc, off);
    if (lane == 0) t2[b * HH + n] = acc + b1[n] + b2[n];
  }
}

// ---------------- 256x256 lagged 4-phase f16 MFMA GEMM + tanh + dot(v) ----------------
// A = hsf [65536 x 1024], B = W1f [1024 x 1024] (both K-major).
// 8 waves: wr = w>>2 (2 in M, 128 rows), wc = w&3 (4 in N, 64 cols).
// LDS: 2 dbuf x 2 halves x 128x64 f16 x {A,B} = 128 KiB (1 block/CU).
// Lagged schedule per K-tile t (buf=t&1):
//   ph1: stage A0,A1(t+1)->nbuf | read A-lo(aLo), B-lo(b0F[t&1]) | MFMA C4(t-1)
//   ph2: stage B0,B1(t+1)->nbuf | read B-hi(b1F)                 | MFMA C1(t)
//   ph3:                          read A-hi(aHi)                 | MFMA C2(t)
//   ph4:                                                           MFMA C3(t)
//        vmcnt(0)  (loads issued >=2 phases ago -> ~free)  | BAR
// Overwrite-safety: regions staged in tile t (-> nbuf) are only ds_read in
// tile t+1, i.e. after the tile-boundary barrier that follows vmcnt(0). A
// region is never staged while any wave has architecturally-unfinished reads
// of it (every ds_read of tile t is lgkm-drained by an MFMA before ph4-end).
// C4(t-1) consumes aHi/b0F read in tile t-1 (registers only, no LDS dep).
// t=0: C4 runs on zero-init fragments (acc += 0*0). C4(15) drains post-loop.
__global__ __launch_bounds__(512, 2) void gemm_energy_8p(
    const f16* __restrict__ hsf, const f16* __restrict__ W1f,
    const float* __restrict__ t2, const float* __restrict__ v,
    float* __restrict__ epart)
{
  __shared__ __align__(16) f16 Asm[2][2][128 * 64];
  __shared__ __align__(16) f16 Bsm[2][2][128 * 64];

  const int tid  = threadIdx.x;
  const int lane = tid & 63;
  const int w    = tid >> 6;      // 0..7
  const int quad = lane >> 4;
  const int l15  = lane & 15;
  const int wr   = w >> 2;        // 0..1 : M
  const int wc   = w & 3;         // 0..3 : N

  // bijective XCD swizzle: 1024 blocks, 4 nb of one mtile consecutive per XCD
  const int l  = blockIdx.x;
  const int x  = l & 7;
  const int j_ = l >> 3;
  const int nb = j_ & 3;
  const int mt = (j_ >> 2) * 8 + x;
  const int mB = mt * 256;
  const int nB = nb * 256;

  const int srow = w * 8 + (lane >> 3);   // 0..63 within one 64-row q-group
  const int sc0  = lane & 7;

  auto stA = [&](int buf, int half, int kt) {
#pragma unroll
    for (int q = 0; q < 2; ++q) {
      const int r  = q * 64 + srow;
      const int cb = sc0 ^ (r & 7);          // pre-swizzled global source
      gload16(&Asm[buf][half][(q * 64 + w * 8) * 64],
              &hsf[(size_t)(mB + half * 128 + r) * HH + kt + cb * 8]);
    }
  };
  auto stB = [&](int buf, int half, int kt) {
#pragma unroll
    for (int q = 0; q < 2; ++q) {
      const int r  = q * 64 + srow;
      const int cb = sc0 ^ (r & 7);
      gload16(&Bsm[buf][half][(q * 64 + w * 8) * 64],
              &W1f[(size_t)(nB + half * 128 + r) * HH + kt + cb * 8]);
    }
  };

  floatx4 acc[8][4];
#pragma unroll
  for (int i = 0; i < 8; ++i)
#pragma unroll
    for (int j = 0; j < 4; ++j) acc[i][j] = (floatx4){0.f, 0.f, 0.f, 0.f};

  // prologue: tile0 fully staged
  stA(0, 0, 0); stA(0, 1, 0); stB(0, 0, 0); stB(0, 1, 0);
  VMC0();
  BARm();

  f16x8 aLo[2][4], aHi[2][4], b0F[2][2][2], b1F[2][2];
  {
    f16x8 z = {};
#pragma unroll
    for (int ks = 0; ks < 2; ++ks) {
#pragma unroll
      for (int i = 0; i < 4; ++i) aHi[ks][i] = z;
#pragma unroll
      for (int j = 0; j < 2; ++j) b0F[1][ks][j] = z;
    }
  }

  const int bhalf  = wc >> 1;
  const int brbase = (wc & 1) * 64;

#pragma unroll 2
  for (int t = 0; t < 16; ++t) {
    const int buf = t & 1, nbuf = buf ^ 1;
    const int pp = buf, pq = nbuf;          // b0F ping-pong
    const int kt1 = (t + 1) * 64;

    // ---------- phase 1 : stage A(t+1) | read A-lo, B-lo | MFMA C4(t-1) ----------
    if (t < 15) { stA(nbuf, 0, kt1); stA(nbuf, 1, kt1); }
#pragma unroll
    for (int ks = 0; ks < 2; ++ks) {
#pragma unroll
      for (int i = 0; i < 4; ++i) {
        const int rl = i * 16 + l15;
        const int cb = (ks * 4 + quad) ^ (rl & 7);
        aLo[ks][i] = *(const f16x8*)&Asm[buf][wr][(rl * 8 + cb) * 8];
      }
#pragma unroll
      for (int j = 0; j < 2; ++j) {
        const int rl = brbase + j * 16 + l15;
        const int cb = (ks * 4 + quad) ^ (rl & 7);
        b0F[pp][ks][j] = *(const f16x8*)&Bsm[buf][bhalf][(rl * 8 + cb) * 8];
      }
    }
    __builtin_amdgcn_s_setprio(1);
#pragma unroll
    for (int ks = 0; ks < 2; ++ks)
#pragma unroll
      for (int i = 0; i < 4; ++i)
#pragma unroll
        for (int j = 0; j < 2; ++j)
          acc[4 + i][j] = __builtin_amdgcn_mfma_f32_16x16x32_f16(aHi[ks][i], b0F[pq][ks][j], acc[4 + i][j], 0, 0, 0);
    __builtin_amdgcn_s_setprio(0);
    BARm();

    // ---------- phase 2 : stage B(t+1) | read B-hi | MFMA C1(t) ----------
    if (t < 15) { stB(nbuf, 0, kt1); stB(nbuf, 1, kt1); }
#pragma unroll
    for (int ks = 0; ks < 2; ++ks)
#pragma unroll
      for (int j = 0; j < 2; ++j) {
        const int rl = brbase + (j + 2) * 16 + l15;
        const int cb = (ks * 4 + quad) ^ (rl & 7);
        b1F[ks][j] = *(const f16x8*)&Bsm[buf][bhalf][(rl * 8 + cb) * 8];
      }
    __builtin_amdgcn_s_setprio(1);
#pragma unroll
    for (int ks = 0; ks < 2; ++ks)
#pragma unroll
      for (int i = 0; i < 4; ++i)
#pragma unroll
        for (int j = 0; j < 2; ++j)
          acc[i][j] = __builtin_amdgcn_mfma_f32_16x16x32_f16(aLo[ks][i], b0F[pp][ks][j], acc[i][j], 0, 0, 0);
    __builtin_amdgcn_s_setprio(0);
    BARm();

    // ---------- phase 3 : read A-hi | MFMA C2(t) ----------
#pragma unroll
    for (int ks = 0; ks < 2; ++ks)
#pragma unroll
      for (int i = 0; i < 4; ++i) {
        const int rl = 64 + i * 16 + l15;
        const int cb = (ks * 4 + quad) ^ (rl & 7);
        aHi[ks][i] = *(const f16x8*)&Asm[buf][wr][(rl * 8 + cb) * 8];
      }
    __builtin_amdgcn_s_setprio(1);
#pragma unroll
    for (int ks = 0; ks < 2; ++ks)
#pragma unroll
      for (int i = 0; i < 4; ++i)
#pragma unroll
        for (int j = 0; j < 2; ++j)
          acc[i][2 + j] = __builtin_amdgcn_mfma_f32_16x16x32_f16(aLo[ks][i], b1F[ks][j], acc[i][2 + j], 0, 0, 0);
    __builtin_amdgcn_s_setprio(0);
    BARm();

    // ---------- phase 4 : MFMA C3(t) | vmcnt(0) ----------
    __builtin_amdgcn_s_setprio(1);
#pragma unroll
    for (int ks = 0; ks < 2; ++ks)
#pragma unroll
      for (int i = 0; i < 4; ++i)
#pragma unroll
        for (int j = 0; j < 2; ++j)
          acc[4 + i][2 + j] = __builtin_amdgcn_mfma_f32_16x16x32_f16(aHi[ks][i], b1F[ks][j], acc[4 + i][2 + j], 0, 0, 0);
    __builtin_amdgcn_s_setprio(0);
    VMC0();   // completes t+1's 8 loads, issued >=2 phases ago
    BARm();
  }

  // drain C4(15): uses aHi(15), b0F[15&1 = 1]
  __builtin_amdgcn_s_setprio(1);
#pragma unroll
  for (int ks = 0; ks < 2; ++ks)
#pragma unroll
    for (int i = 0; i < 4; ++i)
#pragma unroll
      for (int j = 0; j < 2; ++j)
        acc[4 + i][j] = __builtin_amdgcn_mfma_f32_16x16x32_f16(aHi[ks][i], b0F[1][ks][j], acc[4 + i][j], 0, 0, 0);
  __builtin_amdgcn_s_setprio(0);

  // ---- epilogue ----
  // stage t2 slice [32][256] -> LDS (reuse Asm; padded stride 257)
  float* t2s = (float*)&Asm[0][0][0];
  {
    const int r = tid >> 4;            // 0..31
    const int c = (tid & 15) * 16;     // 0..240
#pragma unroll
    for (int q = 0; q < 4; ++q) {
      floatx4 tv = *(const floatx4*)&t2[r * HH + nB + c + q * 4];
      *(floatx4*)&t2s[r * 257 + c + q * 4] = tv;
    }
  }
  __syncthreads();

  // C/D layout col=lane&15, row=quad*4+reg. write epart[p][b][s], p = nb*4+wc
  float vv[4];
#pragma unroll
  for (int j = 0; j < 4; ++j) vv[j] = v[nB + wc * 64 + j * 16 + l15];
#pragma unroll
  for (int i = 0; i < 8; ++i) {
#pragma unroll
    for (int reg = 0; reg < 4; ++reg) {
      const int m = mB + wr * 128 + i * 16 + quad * 4 + reg;
      const int b = m & (BB - 1);
      const int s = m >> 5;
      float rs = 0.f;
#pragma unroll
      for (int j = 0; j < 4; ++j) {
        const int n = wc * 64 + j * 16 + l15;
        rs += tanh_fast(acc[i][j][reg] + t2s[b * 257 + n]) * vv[j];
      }
      rs = dpp_red16(rs);
      if (l15 == 0) epart[(size_t)(nb * 4 + wc) * MM + b * SS + s] = rs;
    }
  }
}

// ---------------- softmax over s per batch column ----------------
__global__ __launch_bounds__(1024) void softmax16t(
    const float* __restrict__ epart, const int* __restrict__ masks,
    float* __restrict__ attn)
{
  const int b = blockIdx.x;
  const int tid = threadIdx.x;   // 0..1023
  __shared__ float redm[16], reds[16];
  float em[2];
  float lmax = -3e38f;
#pragma unroll
  for (int it = 0; it < 2; ++it) {
    const int s = it * 1024 + tid;
    float e = 0.f;
#pragma unroll
    for (int p = 0; p < 16; ++p) e += epart[(size_t)p * MM + b * SS + s];
    if (masks[s * BB + b] == 0) e = -1e10f;
    em[it] = e;
    lmax = fmaxf(lmax, e);
  }
#pragma unroll
  for (int off = 1; off < 64; off <<= 1) lmax = fmaxf(lmax, __shfl_xor(lmax, off));
  if ((tid & 63) == 0) redm[tid >> 6] = lmax;
  __syncthreads();
#pragma unroll
  for (int i = 0; i < 16; ++i) lmax = fmaxf(lmax, redm[i]);
  float lsum = 0.f;
#pragma unroll
  for (int it = 0; it < 2; ++it) { em[it] = __expf(em[it] - lmax); lsum += em[it]; }
#pragma unroll
  for (int off = 1; off < 64; off <<= 1) lsum += __shfl_xor(lsum, off);
  if ((tid & 63) == 0) reds[tid >> 6] = lsum;
  __syncthreads();
  float tsum = 0.f;
#pragma unroll
  for (int i = 0; i < 16; ++i) tsum += reds[i];
  const float inv = 1.0f / tsum;
#pragma unroll
  for (int it = 0; it < 2; ++it) attn[b * SS + it * 1024 + tid] = em[it] * inv;
}

// ---------------- context partials from f16 hs ----------------
__global__ __launch_bounds__(256) void context_f16t(
    const f16* __restrict__ hsf, const float* __restrict__ attn,
    float* __restrict__ ctxp)
{
  const int b  = blockIdx.x;
  const int sc = blockIdx.y;
  const int tid = threadIdx.x;
  __shared__ float sat[64];
  if (tid < 64) sat[tid] = attn[b * SS + sc * 64 + tid];
  __syncthreads();
  floatx4 acc = {0.f, 0.f, 0.f, 0.f};
#pragma unroll 4
  for (int s = 0; s < 64; ++s) {
    const float a = sat[s];
    if (a != 0.f) {   // block-uniform branch; masked rows skip the load
      f16x4 h = *(const f16x4*)&hsf[(size_t)((sc * 64 + s) * BB + b) * HH + tid * 4];
      acc.x += a * (float)h[0];
      acc.y += a * (float)h[1];
      acc.z += a * (float)h[2];
      acc.w += a * (float)h[3];
    }
  }
  *(floatx4*)&ctxp[(size_t)(sc * BB + b) * HH + tid * 4] = acc;
}

__global__ __launch_bounds__(256) void ctx_reduce32(
    const float* __restrict__ ctxp, float* __restrict__ out)
{
  const int i = blockIdx.x * 256 + threadIdx.x;
  float s = 0.f;
#pragma unroll
  for (int sc = 0; sc < 32; ++sc) s += ctxp[(size_t)sc * (BB * HH) + i];
  out[i] = s;
}

// ================= fallback path (round-2, known-passing, 3.4 MB ws) =================
__global__ __launch_bounds__(256) void t2_kernel(
    const float* __restrict__ hidden, const float* __restrict__ W2,
    const float* __restrict__ b1, const float* __restrict__ b2,
    float* __restrict__ t2)
{
  const int gw   = blockIdx.x * 4 + (threadIdx.x >> 6);
  const int n    = gw >> 5;
  const int b    = gw & 31;
  const int lane = threadIdx.x & 63;
  float acc = 0.f;
#pragma unroll
  for (int q = 0; q < 4; ++q) {
    floatx4 hv = *(const floatx4*)&hidden[b * HH + q * 256 + lane * 4];
    floatx4 wv = *(const floatx4*)&W2[(size_t)n * HH + q * 256 + lane * 4];
    acc += hv.x * wv.x + hv.y * wv.y + hv.z * wv.z + hv.w * wv.w;
  }
#pragma unroll
  for (int off = 1; off < 64; off <<= 1) acc += __shfl_xor(acc, off);
  if (lane == 0) t2[b * HH + n] = acc + b1[n] + b2[n];
}

__global__ __launch_bounds__(256) void gemm_energy_fb(
    const float* __restrict__ hs, const float* __restrict__ W1,
    const float* __restrict__ t2, const float* __restrict__ v,
    float* __restrict__ epart)
{
  const int tid = threadIdx.x;
  const int nb  = blockIdx.x;
  const int mB  = blockIdx.y * 128;
  __shared__ __align__(16) f16 Asm[128][72];
  __shared__ __align__(16) f16 Bsm[128][72];
  const int lane = tid & 63;
  const int w    = tid >> 6;
  const int quad = lane >> 4;
  const int l15  = lane & 15;
  floatx4 acc[2][8];
#pragma unroll
  for (int i = 0; i < 2; ++i)
#pragma unroll
    for (int j = 0; j < 8; ++j) acc[i][j] = (floatx4){0.f, 0.f, 0.f, 0.f};
  const int srow = tid >> 4;
  const int scol = (tid & 15) * 4;
  const float* Abase = hs + (size_t)(mB + srow) * HH + scol;
  const float* Bbase = W1 + (size_t)(nb * 128 + srow) * HH + scol;
  for (int kt = 0; kt < HH; kt += 64) {
#pragma unroll
    for (int p = 0; p < 8; ++p) {
      floatx4 fa = *(const floatx4*)(Abase + (size_t)(p * 16) * HH + kt);
      floatx4 fb = *(const floatx4*)(Bbase + (size_t)(p * 16) * HH + kt);
      f16x4 ha = {(f16)fa.x, (f16)fa.y, (f16)fa.z, (f16)fa.w};
      f16x4 hb = {(f16)fb.x, (f16)fb.y, (f16)fb.z, (f16)fb.w};
      *(f16x4*)&Asm[p * 16 + srow][scol] = ha;
      *(f16x4*)&Bsm[p * 16 + srow][scol] = hb;
    }
    __syncthreads();
#pragma unroll
    for (int ks = 0; ks < 2; ++ks) {
      f16x8 af[2], bfr[8];
#pragma unroll
      for (int i = 0; i < 2; ++i)
        af[i] = *(const f16x8*)&Asm[w * 32 + i * 16 + l15][ks * 32 + quad * 8];
#pragma unroll
      for (int j = 0; j < 8; ++j)
        bfr[j] = *(const f16x8*)&Bsm[j * 16 + l15][ks * 32 + quad * 8];
#pragma unroll
      for (int i = 0; i < 2; ++i)
#pragma unroll
        for (int j = 0; j < 8; ++j)
          acc[i][j] = __builtin_amdgcn_mfma_f32_16x16x32_f16(af[i], bfr[j], acc[i][j], 0, 0, 0);
    }
    __syncthreads();
  }
  const int nB = nb * 128;
#pragma unroll
  for (int i = 0; i < 2; ++i) {
#pragma unroll
    for (int reg = 0; reg < 4; ++reg) {
      const int m = mB + w * 32 + i * 16 + quad * 4 + reg;
      const int b = m & (BB - 1);
      float rs = 0.f;
#pragma unroll
      for (int j = 0; j < 8; ++j) {
        const int n = nB + j * 16 + l15;
        rs += tanh_fast(acc[i][j][reg] + t2[b * HH + n]) * v[n];
      }
      rs += __shfl_xor(rs, 1);
      rs += __shfl_xor(rs, 2);
      rs += __shfl_xor(rs, 4);
      rs += __shfl_xor(rs, 8);
      if (l15 == 0) epart[(size_t)nb * MM + m] = rs;
    }
  }
}

__global__ __launch_bounds__(256) void softmax8(
    const float* __restrict__ epart, const int* __restrict__ masks,
    float* __restrict__ attn)
{
  const int b = blockIdx.x;
  const int tid = threadIdx.x;
  __shared__ float redm[4], reds[4];
  float em[8];
  float lmax = -3e38f;
#pragma unroll
  for (int it = 0; it < 8; ++it) {
    const int s = it * 256 + tid;
    float e = 0.f;
#pragma unroll
    for (int p = 0; p < 8; ++p) e += epart[(size_t)p * MM + s * BB + b];
    if (masks[s * BB + b] == 0) e = -1e10f;
    em[it] = e;
    lmax = fmaxf(lmax, e);
  }
#pragma unroll
  for (int off = 1; off < 64; off <<= 1) lmax = fmaxf(lmax, __shfl_xor(lmax, off));
  if ((tid & 63) == 0) redm[tid >> 6] = lmax;
  __syncthreads();
  lmax = fmaxf(fmaxf(redm[0], redm[1]), fmaxf(redm[2], redm[3]));
  float lsum = 0.f;
#pragma unroll
  for (int it = 0; it < 8; ++it) { em[it] = __expf(em[it] - lmax); lsum += em[it]; }
#pragma unroll
  for (int off = 1; off < 64; off <<= 1) lsum += __shfl_xor(lsum, off);
  if ((tid & 63) == 0) reds[tid >> 6] = lsum;
  __syncthreads();
  const float inv = 1.0f / (reds[0] + reds[1] + reds[2] + reds[3]);
#pragma unroll
  for (int it = 0; it < 8; ++it) attn[(it * 256 + tid) * BB + b] = em[it] * inv;
}

__global__ __launch_bounds__(256) void context_fb(
    const float* __restrict__ hs, const float* __restrict__ attn,
    float* __restrict__ ctxp)
{
  const int b  = blockIdx.x;
  const int sc = blockIdx.y;
  const int tid = threadIdx.x;
  floatx4 acc = {0.f, 0.f, 0.f, 0.f};
  for (int s = sc * 256; s < sc * 256 + 256; ++s) {
    const float a = attn[s * BB + b];
    if (a != 0.f) {
      floatx4 h = *(const floatx4*)&hs[(size_t)(s * BB + b) * HH + tid * 4];
      acc.x += a * h.x; acc.y += a * h.y; acc.z += a * h.z; acc.w += a * h.w;
    }
  }
  *(floatx4*)&ctxp[(size_t)(sc * BB + b) * HH + tid * 4] = acc;
}

__global__ __launch_bounds__(256) void ctx_reduce8(
    const float* __restrict__ ctxp, float* __restrict__ out)
{
  const int i = blockIdx.x * 256 + threadIdx.x;
  float s = 0.f;
#pragma unroll
  for (int sc = 0; sc < 8; ++sc) s += ctxp[(size_t)sc * (BB * HH) + i];
  out[i] = s;
}

extern "C" void kernel_launch(void* const* d_in, const int* in_sizes, int n_in,
                              void* d_out, int out_size, void* d_ws, size_t ws_size,
                              hipStream_t stream) {
  const float* hidden = (const float*)d_in[0];  // (1,B,H)
  const float* hs     = (const float*)d_in[1];  // (S,B,H)
  const int*   masks  = (const int*)d_in[2];    // (S,B)
  const float* W1     = (const float*)d_in[3];  // (H,H)
  const float* b1     = (const float*)d_in[4];  // (H,)
  const float* W2     = (const float*)d_in[5];  // (H,H)
  const float* b2     = (const float*)d_in[6];  // (H,)
  const float* v      = (const float*)d_in[7];  // (H,)
  float* out = (float*)d_out;                   // (1,B,H)

  const size_t hsf_b   = (size_t)MM * HH * 2;    // 128 MB
  const size_t w1f_b   = (size_t)HH * HH * 2;    // 2 MB
  const size_t epart_b = (size_t)16 * MM * 4;    // 4 MB
  const size_t attn_b  = (size_t)MM * 4;         // 256 KB
  const size_t t2_b    = (size_t)BB * HH * 4;    // 128 KB
  const size_t ctxp_b  = (size_t)32 * BB * HH * 4; // 4 MB
  const size_t need = hsf_b + w1f_b + epart_b + attn_b + t2_b + ctxp_b;

  if (ws_size >= need) {
    char* p = (char*)d_ws;
    f16*   hsf   = (f16*)p;              p += hsf_b;
    f16*   W1f   = (f16*)p;              p += w1f_b;
    float* epart = (float*)p;            p += epart_b;
    float* attn  = (float*)p;            p += attn_b;
    float* t2    = (float*)p;            p += t2_b;
    float* ctxp  = (float*)p;

    prep_kernel<<<dim3(33280 + 8192), 256, 0, stream>>>(hs, W1, hidden, W2, b1, b2, hsf, W1f, t2);
    gemm_energy_8p<<<dim3(1024), 512, 0, stream>>>(hsf, W1f, t2, v, epart);
    softmax16t<<<dim3(BB), 1024, 0, stream>>>(epart, masks, attn);
    context_f16t<<<dim3(BB, 32), 256, 0, stream>>>(hsf, attn, ctxp);
    ctx_reduce32<<<dim3(BB * HH / 256), 256, 0, stream>>>(ctxp, out);
  } else {
    float* epart = (float*)d_ws;          // 8*MM
    float* attn  = epart + 8 * MM;        // MM
    float* t2    = attn + MM;             // BB*HH
    float* ctxp  = t2 + BB * HH;          // 8*BB*HH

    t2_kernel<<<dim3(BB * HH / 4), 256, 0, stream>>>(hidden, W2, b1, b2, t2);
    gemm_energy_fb<<<dim3(8, MM / 128), 256, 0, stream>>>(hs, W1, t2, v, epart);
    softmax8<<<dim3(BB), 256, 0, stream>>>(epart, masks, attn);
    context_fb<<<dim3(BB, 8), 256, 0, stream>>>(hs, attn, ctxp);
    ctx_reduce8<<<dim3(BB * HH / 256), 256, 0, stream>>>(ctxp, out);
  }
}

// Round 4
// 588.148 us; speedup vs baseline: 1.0616x; 1.0616x over previous
//
#include <hip/hip_runtime.h>
#include <stdint.h>

// Bahdanau additive attention. S=2048, B=32, H=1024.
// context[b,h] = sum_s softmax_s(mask(v . tanh(W1 hs + b1 + W2 h + b2))) * hs
//
// Fast path (needs ~135.5 MB workspace):
//  0) prep: fused {hs,W1 -> f16} + {t2 = hidden.W2^T + b1 + b2}
//  1) gemm_energy_8p: 256x256x(BK=64) f16 MFMA, 8 waves (2Mx4N), 4 phases/
//     K-tile, ONE barrier per phase (R2 schedule, verified 166us/36% MfmaUtil;
//     the R3 lagged variant spilled — reverted). Counted vmcnt(4), XOR-swizzled
//     LDS, global_load_lds 16B, bijective XCD swizzle, t2-in-LDS + tanh+dot(v)
//     + DPP-reduce epilogue -> epart[p][b][s], p = nb*4+wc.
//  2) smax_part: 256 blocks (32 b x 8 chunks of 256 s): sum 16 partials, mask,
//     chunk max + chunk expsum -> stats[b][c]; stages masked e[b][s].
//  3) context8: grid (32 b, 8 sc): merges 8 stats pairs in-register, computes
//     attn = exp(e-gmax)*inv inline, 256-s hs accumulation -> ctxp (1 MB).
//  4) ctx_reduce8 (shared with fallback path).
// Fallback path = round-2 kernels (3.4 MB ws), known-passing, own layouts.

#define SS 2048
#define BB 32
#define HH 1024
#define MM (SS*BB)   // 65536

typedef _Float16 f16;
typedef __attribute__((ext_vector_type(8))) _Float16 f16x8;
typedef __attribute__((ext_vector_type(4))) _Float16 f16x4;
typedef __attribute__((ext_vector_type(4))) float   floatx4;

__device__ __forceinline__ float tanh_fast(float x) {
  float e = __expf(2.0f * x);
  return 1.0f - 2.0f / (e + 1.0f);
}

// async global->LDS, 16B/lane. LDS dest = wave-uniform base + lane*16.
__device__ __forceinline__ void gload16(void* lds_base, const void* gptr) {
  __builtin_amdgcn_global_load_lds(
      (const __attribute__((address_space(1))) uint32_t*)(uintptr_t)gptr,
      (__attribute__((address_space(3))) uint32_t*)(uint32_t)(uintptr_t)lds_base,
      16, 0, 0);
}

#define BAR()   __builtin_amdgcn_s_barrier()
#define VMC4()  asm volatile("s_waitcnt vmcnt(4)" ::: "memory")
#define VMC0()  asm volatile("s_waitcnt vmcnt(0)" ::: "memory")

// 16-lane butterfly sum via DPP: xor1, xor2 (quad_perm), xor7 (row_half_mirror),
// xor15 (row_mirror). Pure VALU - no LDS pipe.
__device__ __forceinline__ float dpp_red16(float x) {
  int t;
  t = __builtin_amdgcn_update_dpp(0, __float_as_int(x), 0xB1, 0xF, 0xF, true);
  x += __int_as_float(t);
  t = __builtin_amdgcn_update_dpp(0, __float_as_int(x), 0x4E, 0xF, 0xF, true);
  x += __int_as_float(t);
  t = __builtin_amdgcn_update_dpp(0, __float_as_int(x), 0x141, 0xF, 0xF, true);
  x += __int_as_float(t);
  t = __builtin_amdgcn_update_dpp(0, __float_as_int(x), 0x140, 0xF, 0xF, true);
  x += __int_as_float(t);
  return x;
}

// ---------------- prep: fp32->f16 convert (hs, W1) + t2 ----------------
__global__ __launch_bounds__(256) void prep_kernel(
    const float* __restrict__ hs, const float* __restrict__ W1,
    const float* __restrict__ hidden, const float* __restrict__ W2,
    const float* __restrict__ b1, const float* __restrict__ b2,
    f16* __restrict__ hsf, f16* __restrict__ W1f, float* __restrict__ t2)
{
  const int bid = blockIdx.x;
  if (bid < 33280) {
    const size_t NH = (size_t)MM * HH;   // 64M floats
    size_t g0 = (size_t)bid * 2048 + threadIdx.x * 4;
    const float* src;
    f16* dst;
    if (g0 < NH) { src = hs; dst = hsf; }
    else         { src = W1 - NH; dst = W1f - NH; }  // offset fold
    floatx4 a = *(const floatx4*)&src[g0];
    floatx4 b = *(const floatx4*)&src[g0 + 1024];
    f16x4 oa = {(f16)a.x,(f16)a.y,(f16)a.z,(f16)a.w};
    f16x4 ob = {(f16)b.x,(f16)b.y,(f16)b.z,(f16)b.w};
    *(f16x4*)&dst[g0] = oa;
    *(f16x4*)&dst[g0 + 1024] = ob;
  } else {
    const int gw   = (bid - 33280) * 4 + (threadIdx.x >> 6);
    const int n    = gw >> 5;
    const int b    = gw & 31;
    const int lane = threadIdx.x & 63;
    float acc = 0.f;
#pragma unroll
    for (int q = 0; q < 4; ++q) {
      floatx4 hv = *(const floatx4*)&hidden[b * HH + q * 256 + lane * 4];
      floatx4 wv = *(const floatx4*)&W2[(size_t)n * HH + q * 256 + lane * 4];
      acc += hv.x * wv.x + hv.y * wv.y + hv.z * wv.z + hv.w * wv.w;
    }
#pragma unroll
    for (int off = 1; off < 64; off <<= 1) acc += __shfl_xor(acc, off);
    if (lane == 0) t2[b * HH + n] = acc + b1[n] + b2[n];
  }
}

// ---------------- 256x256 4-phase f16 MFMA GEMM + tanh + dot(v) ----------------
// (R2 schedule, verified: 166 us, MfmaUtil 36%, 0 main-loop bank conflicts)
// Per K-tile t (buf=t&1), ONE barrier per phase (at phase end):
//   p1 Q(0,0): reads A rows 0-63 + B lo, stages A1(t+1)
//   p2 Q(0,1): reads B hi,              stages B1(t+1)
//   p3 Q(1,1): reads A rows 64-127,     stages B0(t+2)
//   p4 Q(1,0): regs only,               stages A0(t+2), vmcnt(4) (last: 0)
// Overwrite-safety bounded by phase-END barriers (see R2 notes).
__global__ __launch_bounds__(512, 2) void gemm_energy_8p(
    const f16* __restrict__ hsf, const f16* __restrict__ W1f,
    const float* __restrict__ t2, const float* __restrict__ v,
    float* __restrict__ epart)
{
  __shared__ __align__(16) f16 Asm[2][2][128 * 64];
  __shared__ __align__(16) f16 Bsm[2][2][128 * 64];

  const int tid  = threadIdx.x;
  const int lane = tid & 63;
  const int w    = tid >> 6;      // 0..7
  const int quad = lane >> 4;
  const int l15  = lane & 15;
  const int wr   = w >> 2;        // 0..1 : M
  const int wc   = w & 3;         // 0..3 : N

  // bijective XCD swizzle: 1024 blocks, 4 nb of one mtile consecutive per XCD
  const int l  = blockIdx.x;
  const int x  = l & 7;
  const int j_ = l >> 3;
  const int nb = j_ & 3;
  const int mt = (j_ >> 2) * 8 + x;
  const int mB = mt * 256;
  const int nB = nb * 256;

  const int srow = w * 8 + (lane >> 3);   // 0..63 within one 64-row q-group
  const int sc0  = lane & 7;

  auto stA = [&](int buf, int half, int kt) {
#pragma unroll
    for (int q = 0; q < 2; ++q) {
      const int r  = q * 64 + srow;
      const int cb = sc0 ^ (r & 7);          // pre-swizzled global source
      gload16(&Asm[buf][half][(q * 64 + w * 8) * 64],
              &hsf[(size_t)(mB + half * 128 + r) * HH + kt + cb * 8]);
    }
  };
  auto stB = [&](int buf, int half, int kt) {
#pragma unroll
    for (int q = 0; q < 2; ++q) {
      const int r  = q * 64 + srow;
      const int cb = sc0 ^ (r & 7);
      gload16(&Bsm[buf][half][(q * 64 + w * 8) * 64],
              &W1f[(size_t)(nB + half * 128 + r) * HH + kt + cb * 8]);
    }
  };

  floatx4 acc[8][4];
#pragma unroll
  for (int i = 0; i < 8; ++i)
#pragma unroll
    for (int j = 0; j < 4; ++j) acc[i][j] = (floatx4){0.f, 0.f, 0.f, 0.f};

  // prologue: tile0 full + tile1 {B0, A0}; vmcnt(4) -> tile0 landed
  stB(0, 0, 0); stA(0, 0, 0); stA(0, 1, 0); stB(0, 1, 0);
  stB(1, 0, 64); stA(1, 0, 64);
  VMC4();
  BAR();

  f16x8 aF[2][4], b0F[2][2], b1F[2][2];
  const int bhalf  = wc >> 1;
  const int brbase = (wc & 1) * 64;

#pragma unroll 2
  for (int t = 0; t < 16; ++t) {
    const int buf = t & 1, nbuf = buf ^ 1;
    const int kt1 = (t + 1) * 64, kt2 = (t + 2) * 64;

    // ---------- phase 1 : Q(0,0) — 12 ds_read ----------
#pragma unroll
    for (int ks = 0; ks < 2; ++ks) {
#pragma unroll
      for (int i = 0; i < 4; ++i) {
        const int rl = i * 16 + l15;
        const int cb = (ks * 4 + quad) ^ (rl & 7);
        aF[ks][i] = *(const f16x8*)&Asm[buf][wr][(rl * 8 + cb) * 8];
      }
#pragma unroll
      for (int j = 0; j < 2; ++j) {
        const int rl = brbase + j * 16 + l15;
        const int cb = (ks * 4 + quad) ^ (rl & 7);
        b0F[ks][j] = *(const f16x8*)&Bsm[buf][bhalf][(rl * 8 + cb) * 8];
      }
    }
    if (t < 15) stA(nbuf, 1, kt1);
    __builtin_amdgcn_s_setprio(1);
#pragma unroll
    for (int ks = 0; ks < 2; ++ks)
#pragma unroll
      for (int i = 0; i < 4; ++i)
#pragma unroll
        for (int j = 0; j < 2; ++j)
          acc[i][j] = __builtin_amdgcn_mfma_f32_16x16x32_f16(aF[ks][i], b0F[ks][j], acc[i][j], 0, 0, 0);
    __builtin_amdgcn_s_setprio(0);
    BAR();

    // ---------- phase 2 : Q(0,1) — 4 ds_read ----------
#pragma unroll
    for (int ks = 0; ks < 2; ++ks)
#pragma unroll
      for (int j = 0; j < 2; ++j) {
        const int rl = brbase + (j + 2) * 16 + l15;
        const int cb = (ks * 4 + quad) ^ (rl & 7);
        b1F[ks][j] = *(const f16x8*)&Bsm[buf][bhalf][(rl * 8 + cb) * 8];
      }
    if (t < 15) stB(nbuf, 1, kt1);
    __builtin_amdgcn_s_setprio(1);
#pragma unroll
    for (int ks = 0; ks < 2; ++ks)
#pragma unroll
      for (int i = 0; i < 4; ++i)
#pragma unroll
        for (int j = 0; j < 2; ++j)
          acc[i][2 + j] = __builtin_amdgcn_mfma_f32_16x16x32_f16(aF[ks][i], b1F[ks][j], acc[i][2 + j], 0, 0, 0);
    __builtin_amdgcn_s_setprio(0);
    BAR();

    // ---------- phase 3 : Q(1,1) — 8 ds_read ----------
#pragma unroll
    for (int ks = 0; ks < 2; ++ks)
#pragma unroll
      for (int i = 0; i < 4; ++i) {
        const int rl = 64 + i * 16 + l15;
        const int cb = (ks * 4 + quad) ^ (rl & 7);
        aF[ks][i] = *(const f16x8*)&Asm[buf][wr][(rl * 8 + cb) * 8];
      }
    if (t < 14) stB(buf, 0, kt2);
    __builtin_amdgcn_s_setprio(1);
#pragma unroll
    for (int ks = 0; ks < 2; ++ks)
#pragma unroll
      for (int i = 0; i < 4; ++i)
#pragma unroll
        for (int j = 0; j < 2; ++j)
          acc[4 + i][2 + j] = __builtin_amdgcn_mfma_f32_16x16x32_f16(aF[ks][i], b1F[ks][j], acc[4 + i][2 + j], 0, 0, 0);
    __builtin_amdgcn_s_setprio(0);
    BAR();

    // ---------- phase 4 : Q(1,0) — regs only ----------
    if (t < 14) stA(buf, 0, kt2);
    __builtin_amdgcn_s_setprio(1);
#pragma unroll
    for (int ks = 0; ks < 2; ++ks)
#pragma unroll
      for (int i = 0; i < 4; ++i)
#pragma unroll
        for (int j = 0; j < 2; ++j)
          acc[4 + i][j] = __builtin_amdgcn_mfma_f32_16x16x32_f16(aF[ks][i], b0F[ks][j], acc[4 + i][j], 0, 0, 0);
    __builtin_amdgcn_s_setprio(0);
    if (t < 14) { VMC4(); } else { VMC0(); }
    BAR();
  }

  // ---- epilogue ----
  // stage t2 slice [32][256] -> LDS (reuse Asm; padded stride 257)
  float* t2s = (float*)&Asm[0][0][0];
  {
    const int r = tid >> 4;            // 0..31
    const int c = (tid & 15) * 16;     // 0..240
#pragma unroll
    for (int q = 0; q < 4; ++q) {
      floatx4 tv = *(const floatx4*)&t2[r * HH + nB + c + q * 4];
      *(floatx4*)&t2s[r * 257 + c + q * 4] = tv;
    }
  }
  __syncthreads();

  // C/D layout col=lane&15, row=quad*4+reg. write epart[p][b][s], p = nb*4+wc
  float vv[4];
#pragma unroll
  for (int j = 0; j < 4; ++j) vv[j] = v[nB + wc * 64 + j * 16 + l15];
#pragma unroll
  for (int i = 0; i < 8; ++i) {
#pragma unroll
    for (int reg = 0; reg < 4; ++reg) {
      const int m = mB + wr * 128 + i * 16 + quad * 4 + reg;
      const int b = m & (BB - 1);
      const int s = m >> 5;
      float rs = 0.f;
#pragma unroll
      for (int j = 0; j < 4; ++j) {
        const int n = wc * 64 + j * 16 + l15;
        rs += tanh_fast(acc[i][j][reg] + t2s[b * 257 + n]) * vv[j];
      }
      rs = dpp_red16(rs);
      if (l15 == 0) epart[(size_t)(nb * 4 + wc) * MM + b * SS + s] = rs;
    }
  }
}

// ---------------- split softmax pass 1: 256 blocks ----------------
// block = (b, c): s-range [c*256, c*256+256). Sums 16 partials, masks,
// computes chunk max + chunk expsum, stages masked e[b][s].
__global__ __launch_bounds__(256) void smax_part(
    const float* __restrict__ epart, const int* __restrict__ masks,
    float* __restrict__ e_buf, float* __restrict__ stats)
{
  const int b   = blockIdx.x >> 3;
  const int c   = blockIdx.x & 7;
  const int tid = threadIdx.x;
  const int s   = c * 256 + tid;
  __shared__ float redm[4], reds[4];

  float e = 0.f;
#pragma unroll
  for (int p = 0; p < 16; ++p) e += epart[(size_t)p * MM + b * SS + s];
  if (masks[s * BB + b] == 0) e = -1e10f;
  e_buf[b * SS + s] = e;

  float m = e;
#pragma unroll
  for (int off = 1; off < 64; off <<= 1) m = fmaxf(m, __shfl_xor(m, off));
  if ((tid & 63) == 0) redm[tid >> 6] = m;
  __syncthreads();
  m = fmaxf(fmaxf(redm[0], redm[1]), fmaxf(redm[2], redm[3]));

  float x = __expf(e - m);
#pragma unroll
  for (int off = 1; off < 64; off <<= 1) x += __shfl_xor(x, off);
  if ((tid & 63) == 0) reds[tid >> 6] = x;
  __syncthreads();
  if (tid == 0) {
    const float sum = reds[0] + reds[1] + reds[2] + reds[3];
    stats[(b * 8 + c) * 2 + 0] = m;
    stats[(b * 8 + c) * 2 + 1] = sum;
  }
}

// ---------------- fused attn + context partials ----------------
// grid (b=32, sc=8), 256 thr. Merges the 8 per-chunk (max,sum) pairs
// in-register, computes attn inline, accumulates 256 s rows of f16 hs.
__global__ __launch_bounds__(256) void context8(
    const f16* __restrict__ hsf, const float* __restrict__ e_buf,
    const float* __restrict__ stats, float* __restrict__ ctxp)
{
  const int b   = blockIdx.x;
  const int sc  = blockIdx.y;
  const int tid = threadIdx.x;

  float gmax = -3e38f;
#pragma unroll
  for (int c = 0; c < 8; ++c) gmax = fmaxf(gmax, stats[(b * 8 + c) * 2]);
  float gsum = 0.f;
#pragma unroll
  for (int c = 0; c < 8; ++c)
    gsum += stats[(b * 8 + c) * 2 + 1] * __expf(stats[(b * 8 + c) * 2] - gmax);
  const float inv = 1.0f / gsum;

  __shared__ float sat[256];
  sat[tid] = __expf(e_buf[b * SS + sc * 256 + tid] - gmax) * inv;
  __syncthreads();

  floatx4 acc = {0.f, 0.f, 0.f, 0.f};
#pragma unroll 4
  for (int s = 0; s < 256; ++s) {
    const float a = sat[s];
    if (a != 0.f) {   // block-uniform branch; masked rows (exp underflow) skip
      f16x4 h = *(const f16x4*)&hsf[(size_t)((sc * 256 + s) * BB + b) * HH + tid * 4];
      acc.x += a * (float)h[0];
      acc.y += a * (float)h[1];
      acc.z += a * (float)h[2];
      acc.w += a * (float)h[3];
    }
  }
  *(floatx4*)&ctxp[(size_t)(sc * BB + b) * HH + tid * 4] = acc;
}

// ---------------- shared by fast + fallback paths ----------------
__global__ __launch_bounds__(256) void ctx_reduce8(
    const float* __restrict__ ctxp, float* __restrict__ out)
{
  const int i = blockIdx.x * 256 + threadIdx.x;
  float s = 0.f;
#pragma unroll
  for (int sc = 0; sc < 8; ++sc) s += ctxp[(size_t)sc * (BB * HH) + i];
  out[i] = s;
}

// ================= fallback path (round-2, known-passing, 3.4 MB ws) =================
__global__ __launch_bounds__(256) void t2_kernel(
    const float* __restrict__ hidden, const float* __restrict__ W2,
    const float* __restrict__ b1, const float* __restrict__ b2,
    float* __restrict__ t2)
{
  const int gw   = blockIdx.x * 4 + (threadIdx.x >> 6);
  const int n    = gw >> 5;
  const int b    = gw & 31;
  const int lane = threadIdx.x & 63;
  float acc = 0.f;
#pragma unroll
  for (int q = 0; q < 4; ++q) {
    floatx4 hv = *(const floatx4*)&hidden[b * HH + q * 256 + lane * 4];
    floatx4 wv = *(const floatx4*)&W2[(size_t)n * HH + q * 256 + lane * 4];
    acc += hv.x * wv.x + hv.y * wv.y + hv.z * wv.z + hv.w * wv.w;
  }
#pragma unroll
  for (int off = 1; off < 64; off <<= 1) acc += __shfl_xor(acc, off);
  if (lane == 0) t2[b * HH + n] = acc + b1[n] + b2[n];
}

__global__ __launch_bounds__(256) void gemm_energy_fb(
    const float* __restrict__ hs, const float* __restrict__ W1,
    const float* __restrict__ t2, const float* __restrict__ v,
    float* __restrict__ epart)
{
  const int tid = threadIdx.x;
  const int nb  = blockIdx.x;
  const int mB  = blockIdx.y * 128;
  __shared__ __align__(16) f16 Asm[128][72];
  __shared__ __align__(16) f16 Bsm[128][72];
  const int lane = tid & 63;
  const int w    = tid >> 6;
  const int quad = lane >> 4;
  const int l15  = lane & 15;
  floatx4 acc[2][8];
#pragma unroll
  for (int i = 0; i < 2; ++i)
#pragma unroll
    for (int j = 0; j < 8; ++j) acc[i][j] = (floatx4){0.f, 0.f, 0.f, 0.f};
  const int srow = tid >> 4;
  const int scol = (tid & 15) * 4;
  const float* Abase = hs + (size_t)(mB + srow) * HH + scol;
  const float* Bbase = W1 + (size_t)(nb * 128 + srow) * HH + scol;
  for (int kt = 0; kt < HH; kt += 64) {
#pragma unroll
    for (int p = 0; p < 8; ++p) {
      floatx4 fa = *(const floatx4*)(Abase + (size_t)(p * 16) * HH + kt);
      floatx4 fb = *(const floatx4*)(Bbase + (size_t)(p * 16) * HH + kt);
      f16x4 ha = {(f16)fa.x, (f16)fa.y, (f16)fa.z, (f16)fa.w};
      f16x4 hb = {(f16)fb.x, (f16)fb.y, (f16)fb.z, (f16)fb.w};
      *(f16x4*)&Asm[p * 16 + srow][scol] = ha;
      *(f16x4*)&Bsm[p * 16 + srow][scol] = hb;
    }
    __syncthreads();
#pragma unroll
    for (int ks = 0; ks < 2; ++ks) {
      f16x8 af[2], bfr[8];
#pragma unroll
      for (int i = 0; i < 2; ++i)
        af[i] = *(const f16x8*)&Asm[w * 32 + i * 16 + l15][ks * 32 + quad * 8];
#pragma unroll
      for (int j = 0; j < 8; ++j)
        bfr[j] = *(const f16x8*)&Bsm[j * 16 + l15][ks * 32 + quad * 8];
#pragma unroll
      for (int i = 0; i < 2; ++i)
#pragma unroll
        for (int j = 0; j < 8; ++j)
          acc[i][j] = __builtin_amdgcn_mfma_f32_16x16x32_f16(af[i], bfr[j], acc[i][j], 0, 0, 0);
    }
    __syncthreads();
  }
  const int nB = nb * 128;
#pragma unroll
  for (int i = 0; i < 2; ++i) {
#pragma unroll
    for (int reg = 0; reg < 4; ++reg) {
      const int m = mB + w * 32 + i * 16 + quad * 4 + reg;
      const int b = m & (BB - 1);
      float rs = 0.f;
#pragma unroll
      for (int j = 0; j < 8; ++j) {
        const int n = nB + j * 16 + l15;
        rs += tanh_fast(acc[i][j][reg] + t2[b * HH + n]) * v[n];
      }
      rs += __shfl_xor(rs, 1);
      rs += __shfl_xor(rs, 2);
      rs += __shfl_xor(rs, 4);
      rs += __shfl_xor(rs, 8);
      if (l15 == 0) epart[(size_t)nb * MM + m] = rs;
    }
  }
}

__global__ __launch_bounds__(256) void softmax8(
    const float* __restrict__ epart, const int* __restrict__ masks,
    float* __restrict__ attn)
{
  const int b = blockIdx.x;
  const int tid = threadIdx.x;
  __shared__ float redm[4], reds[4];
  float em[8];
  float lmax = -3e38f;
#pragma unroll
  for (int it = 0; it < 8; ++it) {
    const int s = it * 256 + tid;
    float e = 0.f;
#pragma unroll
    for (int p = 0; p < 8; ++p) e += epart[(size_t)p * MM + s * BB + b];
    if (masks[s * BB + b] == 0) e = -1e10f;
    em[it] = e;
    lmax = fmaxf(lmax, e);
  }
#pragma unroll
  for (int off = 1; off < 64; off <<= 1) lmax = fmaxf(lmax, __shfl_xor(lmax, off));
  if ((tid & 63) == 0) redm[tid >> 6] = lmax;
  __syncthreads();
  lmax = fmaxf(fmaxf(redm[0], redm[1]), fmaxf(redm[2], redm[3]));
  float lsum = 0.f;
#pragma unroll
  for (int it = 0; it < 8; ++it) { em[it] = __expf(em[it] - lmax); lsum += em[it]; }
#pragma unroll
  for (int off = 1; off < 64; off <<= 1) lsum += __shfl_xor(lsum, off);
  if ((tid & 63) == 0) reds[tid >> 6] = lsum;
  __syncthreads();
  const float inv = 1.0f / (reds[0] + reds[1] + reds[2] + reds[3]);
#pragma unroll
  for (int it = 0; it < 8; ++it) attn[(it * 256 + tid) * BB + b] = em[it] * inv;
}

__global__ __launch_bounds__(256) void context_fb(
    const float* __restrict__ hs, const float* __restrict__ attn,
    float* __restrict__ ctxp)
{
  const int b  = blockIdx.x;
  const int sc = blockIdx.y;
  const int tid = threadIdx.x;
  floatx4 acc = {0.f, 0.f, 0.f, 0.f};
  for (int s = sc * 256; s < sc * 256 + 256; ++s) {
    const float a = attn[s * BB + b];
    if (a != 0.f) {
      floatx4 h = *(const floatx4*)&hs[(size_t)(s * BB + b) * HH + tid * 4];
      acc.x += a * h.x; acc.y += a * h.y; acc.z += a * h.z; acc.w += a * h.w;
    }
  }
  *(floatx4*)&ctxp[(size_t)(sc * BB + b) * HH + tid * 4] = acc;
}

extern "C" void kernel_launch(void* const* d_in, const int* in_sizes, int n_in,
                              void* d_out, int out_size, void* d_ws, size_t ws_size,
                              hipStream_t stream) {
  const float* hidden = (const float*)d_in[0];  // (1,B,H)
  const float* hs     = (const float*)d_in[1];  // (S,B,H)
  const int*   masks  = (const int*)d_in[2];    // (S,B)
  const float* W1     = (const float*)d_in[3];  // (H,H)
  const float* b1     = (const float*)d_in[4];  // (H,)
  const float* W2     = (const float*)d_in[5];  // (H,H)
  const float* b2     = (const float*)d_in[6];  // (H,)
  const float* v      = (const float*)d_in[7];  // (H,)
  float* out = (float*)d_out;                   // (1,B,H)

  const size_t hsf_b   = (size_t)MM * HH * 2;      // 128 MB
  const size_t w1f_b   = (size_t)HH * HH * 2;      // 2 MB
  const size_t epart_b = (size_t)16 * MM * 4;      // 4 MB
  const size_t ebuf_b  = (size_t)MM * 4;           // 256 KB
  const size_t stats_b = (size_t)4096;             // 32*8*2 f32, padded
  const size_t t2_b    = (size_t)BB * HH * 4;      // 128 KB
  const size_t ctxp_b  = (size_t)8 * BB * HH * 4;  // 1 MB
  const size_t need = hsf_b + w1f_b + epart_b + ebuf_b + stats_b + t2_b + ctxp_b;

  if (ws_size >= need) {
    char* p = (char*)d_ws;
    f16*   hsf   = (f16*)p;              p += hsf_b;
    f16*   W1f   = (f16*)p;              p += w1f_b;
    float* epart = (float*)p;            p += epart_b;
    float* e_buf = (float*)p;            p += ebuf_b;
    float* stats = (float*)p;            p += stats_b;
    float* t2    = (float*)p;            p += t2_b;
    float* ctxp  = (float*)p;

    prep_kernel<<<dim3(33280 + 8192), 256, 0, stream>>>(hs, W1, hidden, W2, b1, b2, hsf, W1f, t2);
    gemm_energy_8p<<<dim3(1024), 512, 0, stream>>>(hsf, W1f, t2, v, epart);
    smax_part<<<dim3(256), 256, 0, stream>>>(epart, masks, e_buf, stats);
    context8<<<dim3(BB, 8), 256, 0, stream>>>(hsf, e_buf, stats, ctxp);
    ctx_reduce8<<<dim3(BB * HH / 256), 256, 0, stream>>>(ctxp, out);
  } else {
    float* epart = (float*)d_ws;          // 8*MM
    float* attn  = epart + 8 * MM;        // MM
    float* t2    = attn + MM;             // BB*HH
    float* ctxp  = t2 + BB * HH;          // 8*BB*HH

    t2_kernel<<<dim3(BB * HH / 4), 256, 0, stream>>>(hidden, W2, b1, b2, t2);
    gemm_energy_fb<<<dim3(8, MM / 128), 256, 0, stream>>>(hs, W1, t2, v, epart);
    softmax8<<<dim3(BB), 256, 0, stream>>>(epart, masks, attn);
    context_fb<<<dim3(BB, 8), 256, 0, stream>>>(hs, attn, ctxp);
    ctx_reduce8<<<dim3(BB * HH / 256), 256, 0, stream>>>(ctxp, out);
  }
}